// Round 1
// baseline (596.861 us; speedup 1.0000x reference)
//
#include <hip/hip_runtime.h>
#include <cmath>

#define DEV __device__ __forceinline__

DEV unsigned enc_f(float x) { unsigned u = __float_as_uint(x); return (u >> 31) ? ~u : (u | 0x80000000u); }
DEV float dec_f(unsigned u) { return __uint_as_float((u >> 31) ? (u & 0x7FFFFFFFu) : ~u); }

// ---------------- encoder: z_q, cl = zq@Wl0_bot, crb = zq@Wr0_bot + b0 ----------------
__global__ __launch_bounds__(256) void encoder_kernel(
    const int* __restrict__ ids, const float* __restrict__ rssi,
    const float* __restrict__ emb, const float* __restrict__ ew, const float* __restrict__ eb,
    const float* __restrict__ Wl0, const float* __restrict__ Wr0, const float* __restrict__ b0,
    float* __restrict__ zout, int NQ)
{
    __shared__ float zsh[4][64];
    __shared__ float zq[64];
    int j = threadIdx.x & 63;
    int g = threadIdx.x >> 6;
    float acc = 0.f;
    for (int q = g; q < NQ; q += 4) {
        int id = ids[q];
        const float* e = emb + (size_t)id * 32;
        float p = eb[j];
#pragma unroll
        for (int k = 0; k < 32; ++k) p = fmaf(e[k], ew[k * 64 + j], p);
        p = fmaf(rssi[q], ew[32 * 64 + j], p);
        acc += fmaxf(p, 0.f);
    }
    zsh[g][j] = acc;
    __syncthreads();
    if (g == 0) {
        float z = (zsh[0][j] + zsh[1][j] + zsh[2][j] + zsh[3][j]) / (float)NQ;
        zq[j] = z;
        zout[j] = z;
    }
    __syncthreads();
    if (g == 0) {
        float cl = 0.f, cr = 0.f;
        for (int k = 0; k < 64; ++k) {
            float zk = zq[k];
            cl = fmaf(zk, Wl0[(128 + k) * 64 + j], cl);
            cr = fmaf(zk, Wr0[(128 + k) * 64 + j], cr);
        }
        zout[64 + j] = cl;
        zout[128 + j] = cr + b0[j];
    }
}

// ---------------- CSR build ----------------
__global__ __launch_bounds__(256) void count_kernel(const int* __restrict__ dst, int* __restrict__ deg, int E)
{
    int i = blockIdx.x * 256 + threadIdx.x;
    if (i < E) atomicAdd(&deg[dst[i]], 1);
}

__global__ __launch_bounds__(1024) void scan_kernel(const int* __restrict__ deg, int* __restrict__ offs,
                                                    int* __restrict__ cursor, int N)
{
    __shared__ int sums[1024];
    int t = threadIdx.x;
    int C = (N + 1023) >> 10;
    int c0 = t * C;
    int c1 = min(c0 + C, N);
    int s = 0;
    for (int i = c0; i < c1; ++i) s += deg[i];
    sums[t] = s;
    __syncthreads();
    for (int d = 1; d < 1024; d <<= 1) {
        int v = (t >= d) ? sums[t - d] : 0;
        __syncthreads();
        sums[t] += v;
        __syncthreads();
    }
    int run = (t > 0) ? sums[t - 1] : 0;
    for (int i = c0; i < c1; ++i) {
        offs[i] = run;
        cursor[i] = run;
        run += deg[i];
    }
    if (t == 1023) offs[N] = run;
}

__global__ __launch_bounds__(256) void scatter_kernel(const int* __restrict__ src, const int* __restrict__ dst,
                                                      int* __restrict__ cursor, int* __restrict__ srcs, int E)
{
    int i = blockIdx.x * 256 + threadIdx.x;
    if (i < E) {
        int p = atomicAdd(&cursor[dst[i]], 1);
        srcs[p] = src[i];
    }
}

// ---------------- tiled fp32 GEMM: O1 = A@B1 (+add1), O2 = A@B2 (+add2) ----------------
// A [N,K] row-major, B [K,64] row-major. 64-row tile, 256 threads.
template <int K, bool DUAL, bool RELU>
__global__ __launch_bounds__(256) void gemm_kernel(
    const float* __restrict__ A, const float* __restrict__ B1, const float* __restrict__ B2,
    const float* __restrict__ add1, const float* __restrict__ add2,
    float* __restrict__ O1, float* __restrict__ O2, int N)
{
    constexpr int BC = DUAL ? 128 : 64;
    constexpr int TC = DUAL ? 4 : 2;
    __shared__ float As[32][68];   // [k][row], pad 68: 16B-aligned b128 reads, 2-way banks (free)
    __shared__ float Bs[32][BC];

    const int tid = threadIdx.x;
    const int cg = tid & 31;
    const int rg = tid >> 5;
    const int row0 = blockIdx.x * 64;

    float acc[8][TC];
#pragma unroll
    for (int i = 0; i < 8; ++i)
#pragma unroll
        for (int j = 0; j < TC; ++j) acc[i][j] = 0.f;

    for (int kc = 0; kc < K; kc += 32) {
        // stage A transposed: 64 rows x 32 k
#pragma unroll
        for (int i = 0; i < 2; ++i) {
            int vi = i * 256 + tid;
            int r = vi >> 3;
            int k4 = (vi & 7) << 2;
            int row = row0 + r;
            float4 v = make_float4(0.f, 0.f, 0.f, 0.f);
            if (row < N) v = *(const float4*)(A + (size_t)row * K + kc + k4);
            As[k4 + 0][r] = v.x; As[k4 + 1][r] = v.y; As[k4 + 2][r] = v.z; As[k4 + 3][r] = v.w;
        }
        if constexpr (DUAL) {
#pragma unroll
            for (int i = 0; i < 4; ++i) {
                int vi = i * 256 + tid;
                int k = vi >> 5;
                int c = (vi & 31) << 2;
                const float* sp = (c < 64) ? (B1 + (size_t)(kc + k) * 64 + c)
                                           : (B2 + (size_t)(kc + k) * 64 + (c - 64));
                *(float4*)&Bs[k][c] = *(const float4*)sp;
            }
        } else {
#pragma unroll
            for (int i = 0; i < 2; ++i) {
                int vi = i * 256 + tid;
                int k = vi >> 4;
                int c = (vi & 15) << 2;
                *(float4*)&Bs[k][c] = *(const float4*)(B1 + (size_t)(kc + k) * 64 + c);
            }
        }
        __syncthreads();
#pragma unroll
        for (int k = 0; k < 32; ++k) {
            float4 a0 = *(const float4*)&As[k][rg * 8];
            float4 a1 = *(const float4*)&As[k][rg * 8 + 4];
            float a[8] = {a0.x, a0.y, a0.z, a0.w, a1.x, a1.y, a1.z, a1.w};
            float b[TC];
            if constexpr (DUAL) {
                float4 bv = *(const float4*)&Bs[k][cg * 4];
                b[0] = bv.x; b[1] = bv.y; b[2] = bv.z; b[3] = bv.w;
            } else {
                float2 bv = *(const float2*)&Bs[k][cg * 2];
                b[0] = bv.x; b[1] = bv.y;
            }
#pragma unroll
            for (int i = 0; i < 8; ++i)
#pragma unroll
                for (int j = 0; j < TC; ++j)
                    acc[i][j] = fmaf(a[i], b[j], acc[i][j]);
        }
        __syncthreads();
    }

    int c0 = cg * TC;
    if constexpr (DUAL) {
        float* O; int c; const float* addp;
        if (c0 < 64) { O = O1; c = c0; addp = add1; }
        else         { O = O2; c = c0 - 64; addp = add2; }
        float4 av = make_float4(0.f, 0.f, 0.f, 0.f);
        if (addp) av = *(const float4*)(addp + c);
#pragma unroll
        for (int i = 0; i < 8; ++i) {
            int row = row0 + rg * 8 + i;
            if (row < N) {
                float4 o;
                o.x = acc[i][0] + av.x; o.y = acc[i][1] + av.y;
                o.z = acc[i][2] + av.z; o.w = acc[i][3] + av.w;
                if constexpr (RELU) {
                    o.x = fmaxf(o.x, 0.f); o.y = fmaxf(o.y, 0.f);
                    o.z = fmaxf(o.z, 0.f); o.w = fmaxf(o.w, 0.f);
                }
                *(float4*)(O + (size_t)row * 64 + c) = o;
            }
        }
    } else {
        float2 av = make_float2(0.f, 0.f);
        if (add1) av = *(const float2*)(add1 + c0);
#pragma unroll
        for (int i = 0; i < 8; ++i) {
            int row = row0 + rg * 8 + i;
            if (row < N) {
                float2 o;
                o.x = acc[i][0] + av.x; o.y = acc[i][1] + av.y;
                if constexpr (RELU) { o.x = fmaxf(o.x, 0.f); o.y = fmaxf(o.y, 0.f); }
                *(float2*)(O1 + (size_t)row * 64 + c0) = o;
            }
        }
    }
}

// ---------------- aggregation: h = relu(segsum(m)/clip(deg,1) + [deg>0]*cl + r) ----------------
__global__ __launch_bounds__(256) void agg_kernel(
    const float* __restrict__ m, const float* __restrict__ r,
    const int* __restrict__ off, const int* __restrict__ srcs,
    const float* __restrict__ cl, float* __restrict__ hout, int N)
{
    int node = blockIdx.x * 4 + threadIdx.y;
    if (node >= N) return;
    int lane = threadIdx.x;
    int e0 = off[node], e1 = off[node + 1];
    float a0 = 0.f, a1 = 0.f;
    int e = e0;
    for (; e + 1 < e1; e += 2) {
        int s0 = srcs[e], s1 = srcs[e + 1];
        a0 += m[(size_t)s0 * 64 + lane];
        a1 += m[(size_t)s1 * 64 + lane];
    }
    if (e < e1) a0 += m[(size_t)srcs[e] * 64 + lane];
    int deg = e1 - e0;
    float v = (a0 + a1) / (float)(deg > 0 ? deg : 1) + r[(size_t)node * 64 + lane];
    if (cl != nullptr && deg > 0) v += cl[lane];
    hout[(size_t)node * 64 + lane] = fmaxf(v, 0.f);
}

// ---------------- scorer dot: s = t@w2 + b2 ----------------
__global__ __launch_bounds__(256) void score_kernel(const float* __restrict__ t, const float* __restrict__ w2,
                                                    const float* __restrict__ b2, float* __restrict__ s, int N)
{
    int node = blockIdx.x * 4 + threadIdx.y;
    if (node >= N) return;
    int lane = threadIdx.x;
    float v = t[(size_t)node * 64 + lane] * w2[lane];
#pragma unroll
    for (int d = 32; d >= 1; d >>= 1) v += __shfl_xor(v, d, 64);
    if (lane == 0) s[node] = v + b2[0];
}

// ---------------- softmax reductions ----------------
__global__ __launch_bounds__(256) void max_kernel(const float* __restrict__ s, unsigned* __restrict__ red, int N)
{
    float m = -3.402823466e+38f;
    for (int i = blockIdx.x * blockDim.x + threadIdx.x; i < N; i += gridDim.x * blockDim.x)
        m = fmaxf(m, s[i]);
#pragma unroll
    for (int d = 32; d >= 1; d >>= 1) m = fmaxf(m, __shfl_xor(m, d, 64));
    if ((threadIdx.x & 63) == 0) atomicMax(red, enc_f(m));
}

__global__ __launch_bounds__(256) void sum_kernel(const float* __restrict__ s, const float* __restrict__ pos,
                                                  const unsigned* __restrict__ redmax, float* __restrict__ red, int N)
{
    float mx = dec_f(redmax[0]);
    float se = 0.f, px = 0.f, py = 0.f;
    for (int i = blockIdx.x * blockDim.x + threadIdx.x; i < N; i += gridDim.x * blockDim.x) {
        float e = expf(s[i] - mx);
        se += e;
        px = fmaf(e, pos[2 * i], px);
        py = fmaf(e, pos[2 * i + 1], py);
    }
#pragma unroll
    for (int d = 32; d >= 1; d >>= 1) {
        se += __shfl_xor(se, d, 64);
        px += __shfl_xor(px, d, 64);
        py += __shfl_xor(py, d, 64);
    }
    if ((threadIdx.x & 63) == 0) {
        atomicAdd(&red[1], se);
        atomicAdd(&red[2], px);
        atomicAdd(&red[3], py);
    }
}

__global__ __launch_bounds__(256) void final_kernel(const float* __restrict__ s, const unsigned* __restrict__ redmax,
                                                    const float* __restrict__ red, float* __restrict__ out, int N)
{
    float mx = dec_f(redmax[0]);
    float S = red[1];
    int i = blockIdx.x * blockDim.x + threadIdx.x;
    if (i < N) out[2 + i] = expf(s[i] - mx) / S;
    if (i == 0) {
        out[0] = red[2] / S;
        out[1] = red[3] / S;
    }
}

extern "C" void kernel_launch(void* const* d_in, const int* in_sizes, int n_in,
                              void* d_out, int out_size, void* d_ws, size_t ws_size,
                              hipStream_t stream)
{
    const float* x    = (const float*)d_in[0];
    const float* pos  = (const float*)d_in[1];
    const int*   ei   = (const int*)d_in[2];
    const int*   qids = (const int*)d_in[3];
    const float* qrs  = (const float*)d_in[4];
    const float* emb  = (const float*)d_in[5];
    const float* ew   = (const float*)d_in[6];
    const float* eb   = (const float*)d_in[7];
    const float* Wl0  = (const float*)d_in[8];
    const float* Wr0  = (const float*)d_in[9];
    const float* b0   = (const float*)d_in[10];
    const float* Wl1  = (const float*)d_in[11];
    const float* Wr1  = (const float*)d_in[12];
    const float* b1   = (const float*)d_in[13];
    const float* Wl2  = (const float*)d_in[14];
    const float* Wr2  = (const float*)d_in[15];
    const float* b2   = (const float*)d_in[16];
    const float* sw1  = (const float*)d_in[17];
    const float* sb1  = (const float*)d_in[18];
    const float* sw2  = (const float*)d_in[19];
    const float* sb2  = (const float*)d_in[20];

    const int N  = in_sizes[0] / 128;
    const int E  = in_sizes[2] / 2;
    const int NQ = in_sizes[3];

    char* base = (char*)d_ws;
    size_t wsoff = 0;
    auto take = [&](size_t bytes) -> char* {
        char* p = base + wsoff;
        wsoff = (wsoff + bytes + 255) & ~(size_t)255;
        return p;
    };
    int*      deg    = (int*)take((size_t)N * 4);
    int*      offs   = (int*)take((size_t)(N + 1) * 4);
    int*      cursor = (int*)take((size_t)N * 4);
    int*      srcs   = (int*)take((size_t)E * 4);
    float*    zout   = (float*)take(192 * 4);   // zq[64], cl[64], crb[64]
    unsigned* red    = (unsigned*)take(16);     // [0]=max(enc) [1]=sumexp [2]=px [3]=py
    float*    mbuf   = (float*)take((size_t)N * 64 * 4);
    float*    rbuf   = (float*)take((size_t)N * 64 * 4);
    float*    hbuf   = (float*)take((size_t)N * 64 * 4);
    float*    sbuf   = (float*)take((size_t)N * 4);
    (void)ws_size; (void)n_in; (void)out_size;

    const int* esrc = ei;
    const int* edst = ei + E;

    hipMemsetAsync(deg, 0, (size_t)N * 4, stream);
    hipMemsetAsync(red, 0, 16, stream);

    encoder_kernel<<<1, 256, 0, stream>>>(qids, qrs, emb, ew, eb, Wl0, Wr0, b0, zout, NQ);
    count_kernel<<<(E + 255) / 256, 256, 0, stream>>>(edst, deg, E);
    scan_kernel<<<1, 1024, 0, stream>>>(deg, offs, cursor, N);
    scatter_kernel<<<(E + 255) / 256, 256, 0, stream>>>(esrc, edst, cursor, srcs, E);

    int gblocks = (N + 63) / 64;
    dim3 ablk(64, 4);
    int ablocks = (N + 3) / 4;

    // layer 0: m = x@Wl0_top, r = x@Wr0_top + (zq@Wr0_bot + b0)
    gemm_kernel<128, true, false><<<gblocks, 256, 0, stream>>>(x, Wl0, Wr0, nullptr, zout + 128, mbuf, rbuf, N);
    agg_kernel<<<ablocks, ablk, 0, stream>>>(mbuf, rbuf, offs, srcs, zout + 64, hbuf, N);
    // layer 1
    gemm_kernel<64, true, false><<<gblocks, 256, 0, stream>>>(hbuf, Wl1, Wr1, nullptr, b1, mbuf, rbuf, N);
    agg_kernel<<<ablocks, ablk, 0, stream>>>(mbuf, rbuf, offs, srcs, nullptr, hbuf, N);
    // layer 2
    gemm_kernel<64, true, false><<<gblocks, 256, 0, stream>>>(hbuf, Wl2, Wr2, nullptr, b2, mbuf, rbuf, N);
    agg_kernel<<<ablocks, ablk, 0, stream>>>(mbuf, rbuf, offs, srcs, nullptr, hbuf, N);
    // scorer
    gemm_kernel<64, false, true><<<gblocks, 256, 0, stream>>>(hbuf, sw1, nullptr, sb1, nullptr, mbuf, nullptr, N);
    score_kernel<<<ablocks, ablk, 0, stream>>>(mbuf, sw2, sb2, sbuf, N);

    max_kernel<<<128, 256, 0, stream>>>(sbuf, red, N);
    sum_kernel<<<128, 256, 0, stream>>>(sbuf, pos, red, (float*)red, N);
    final_kernel<<<(N + 255) / 256, 256, 0, stream>>>(sbuf, red, (float*)red, (float*)d_out, N);
}

// Round 2
// 414.611 us; speedup vs baseline: 1.4396x; 1.4396x over previous
//
#include <hip/hip_runtime.h>
#include <cmath>
#include <cfloat>

#define DEV __device__ __forceinline__

DEV unsigned enc_f(float x) { unsigned u = __float_as_uint(x); return (u >> 31) ? ~u : (u | 0x80000000u); }
DEV float dec_f(unsigned u) { return __uint_as_float((u >> 31) ? (u & 0x7FFFFFFFu) : ~u); }

// ---------------- encoder: z_q, cl = zq@Wl0_bot, crb = zq@Wr0_bot + b0 ----------------
__global__ __launch_bounds__(256) void encoder_kernel(
    const int* __restrict__ ids, const float* __restrict__ rssi,
    const float* __restrict__ emb, const float* __restrict__ ew, const float* __restrict__ eb,
    const float* __restrict__ Wl0, const float* __restrict__ Wr0, const float* __restrict__ b0,
    float* __restrict__ zout, int NQ)
{
    __shared__ float zsh[4][64];
    __shared__ float zq[64];
    int j = threadIdx.x & 63;
    int g = threadIdx.x >> 6;
    float acc = 0.f;
    for (int q = g; q < NQ; q += 4) {
        int id = ids[q];
        const float* e = emb + (size_t)id * 32;
        float p = eb[j];
#pragma unroll
        for (int k = 0; k < 32; ++k) p = fmaf(e[k], ew[k * 64 + j], p);
        p = fmaf(rssi[q], ew[32 * 64 + j], p);
        acc += fmaxf(p, 0.f);
    }
    zsh[g][j] = acc;
    __syncthreads();
    if (g == 0) {
        float z = (zsh[0][j] + zsh[1][j] + zsh[2][j] + zsh[3][j]) / (float)NQ;
        zq[j] = z;
        zout[j] = z;
    }
    __syncthreads();
    if (g == 0) {
        float cl = 0.f, cr = 0.f;
        for (int k = 0; k < 64; ++k) {
            float zk = zq[k];
            cl = fmaf(zk, Wl0[(128 + k) * 64 + j], cl);
            cr = fmaf(zk, Wr0[(128 + k) * 64 + j], cr);
        }
        zout[64 + j] = cl;
        zout[128 + j] = cr + b0[j];
    }
}

// ---------------- CSR build ----------------
__global__ __launch_bounds__(256) void count_kernel(const int* __restrict__ dst, int* __restrict__ deg, int E)
{
    int i = blockIdx.x * 256 + threadIdx.x;
    if (i < E) atomicAdd(&deg[dst[i]], 1);
}

// phase A: per-block inclusive scan -> local exclusive in offs, block sum to bsum
__global__ __launch_bounds__(256) void scanA_kernel(const int* __restrict__ deg, int* __restrict__ offs,
                                                    int* __restrict__ bsum, int N)
{
    __shared__ int sh[256];
    int t = threadIdx.x;
    int i = blockIdx.x * 256 + t;
    int v = (i < N) ? deg[i] : 0;
    sh[t] = v;
    __syncthreads();
#pragma unroll
    for (int d = 1; d < 256; d <<= 1) {
        int u = (t >= d) ? sh[t - d] : 0;
        __syncthreads();
        sh[t] += u;
        __syncthreads();
    }
    if (i < N) offs[i] = sh[t] - v;
    if (t == 255) bsum[blockIdx.x] = sh[255];
}

// phase B: scan block sums (NB <= 256*chunk), write bbase, offs[N]=total
__global__ __launch_bounds__(256) void scanB_kernel(const int* __restrict__ bsum, int* __restrict__ bbase,
                                                    int* __restrict__ offs, int NB, int N)
{
    __shared__ int sh[256];
    int t = threadIdx.x;
    int C = (NB + 255) >> 8;
    int c0 = t * C, c1 = min(c0 + C, NB);
    int s = 0;
    for (int i = c0; i < c1; ++i) s += bsum[i];
    sh[t] = s;
    __syncthreads();
#pragma unroll
    for (int d = 1; d < 256; d <<= 1) {
        int u = (t >= d) ? sh[t - d] : 0;
        __syncthreads();
        sh[t] += u;
        __syncthreads();
    }
    int run = (t > 0) ? sh[t - 1] : 0;
    for (int i = c0; i < c1; ++i) { bbase[i] = run; run += bsum[i]; }
    if (t == 255) offs[N] = sh[255];
}

// phase C: add block base, init cursor
__global__ __launch_bounds__(256) void scanC_kernel(int* __restrict__ offs, int* __restrict__ cursor,
                                                    const int* __restrict__ bbase, int N)
{
    int i = blockIdx.x * 256 + threadIdx.x;
    if (i < N) {
        int o = offs[i] + bbase[blockIdx.x];
        offs[i] = o;
        cursor[i] = o;
    }
}

__global__ __launch_bounds__(256) void scatter_kernel(const int* __restrict__ src, const int* __restrict__ dst,
                                                      int* __restrict__ cursor, int* __restrict__ srcs, int E)
{
    int i = blockIdx.x * 256 + threadIdx.x;
    if (i < E) {
        int p = atomicAdd(&cursor[dst[i]], 1);
        srcs[p] = src[i];
    }
}

// ---------------- tiled fp32 GEMM (dual output): O1 = A@B1 (+add1), O2 = A@B2 (+add2) ----------------
template <int K>
__global__ __launch_bounds__(256) void gemm_kernel(
    const float* __restrict__ A, const float* __restrict__ B1, const float* __restrict__ B2,
    const float* __restrict__ add1, const float* __restrict__ add2,
    float* __restrict__ O1, float* __restrict__ O2, int N)
{
    __shared__ float As[32][68];   // [k][row], pad 68: 16B-aligned b128 reads, 2-way banks (free)
    __shared__ float Bs[32][128];

    const int tid = threadIdx.x;
    const int cg = tid & 31;
    const int rg = tid >> 5;
    const int row0 = blockIdx.x * 64;

    float acc[8][4];
#pragma unroll
    for (int i = 0; i < 8; ++i)
#pragma unroll
        for (int j = 0; j < 4; ++j) acc[i][j] = 0.f;

    for (int kc = 0; kc < K; kc += 32) {
#pragma unroll
        for (int i = 0; i < 2; ++i) {
            int vi = i * 256 + tid;
            int r = vi >> 3;
            int k4 = (vi & 7) << 2;
            int row = row0 + r;
            float4 v = make_float4(0.f, 0.f, 0.f, 0.f);
            if (row < N) v = *(const float4*)(A + (size_t)row * K + kc + k4);
            As[k4 + 0][r] = v.x; As[k4 + 1][r] = v.y; As[k4 + 2][r] = v.z; As[k4 + 3][r] = v.w;
        }
#pragma unroll
        for (int i = 0; i < 4; ++i) {
            int vi = i * 256 + tid;
            int k = vi >> 5;
            int c = (vi & 31) << 2;
            const float* sp = (c < 64) ? (B1 + (size_t)(kc + k) * 64 + c)
                                       : (B2 + (size_t)(kc + k) * 64 + (c - 64));
            *(float4*)&Bs[k][c] = *(const float4*)sp;
        }
        __syncthreads();
#pragma unroll
        for (int k = 0; k < 32; ++k) {
            float4 a0 = *(const float4*)&As[k][rg * 8];
            float4 a1 = *(const float4*)&As[k][rg * 8 + 4];
            float a[8] = {a0.x, a0.y, a0.z, a0.w, a1.x, a1.y, a1.z, a1.w};
            float4 bv = *(const float4*)&Bs[k][cg * 4];
            float b[4] = {bv.x, bv.y, bv.z, bv.w};
#pragma unroll
            for (int i = 0; i < 8; ++i)
#pragma unroll
                for (int j = 0; j < 4; ++j)
                    acc[i][j] = fmaf(a[i], b[j], acc[i][j]);
        }
        __syncthreads();
    }

    int c0 = cg * 4;
    float* O; int c; const float* addp;
    if (c0 < 64) { O = O1; c = c0; addp = add1; }
    else         { O = O2; c = c0 - 64; addp = add2; }
    float4 av = make_float4(0.f, 0.f, 0.f, 0.f);
    if (addp) av = *(const float4*)(addp + c);
#pragma unroll
    for (int i = 0; i < 8; ++i) {
        int row = row0 + rg * 8 + i;
        if (row < N) {
            float4 o;
            o.x = acc[i][0] + av.x; o.y = acc[i][1] + av.y;
            o.z = acc[i][2] + av.z; o.w = acc[i][3] + av.w;
            *(float4*)(O + (size_t)row * 64 + c) = o;
        }
    }
}

// ---------------- fused scorer: s = relu(h@w1+b1)@w2 + b2, block max -> atomicMax ----------------
__global__ __launch_bounds__(256) void scorer_gemm_kernel(
    const float* __restrict__ A, const float* __restrict__ B1,
    const float* __restrict__ bias, const float* __restrict__ w2, const float* __restrict__ b2,
    float* __restrict__ sbuf, unsigned* __restrict__ red, int N)
{
    __shared__ float As[32][68];
    __shared__ float Bs[32][64];
    __shared__ float smax[256];

    const int tid = threadIdx.x;
    const int cg = tid & 31;
    const int rg = tid >> 5;
    const int row0 = blockIdx.x * 64;

    float acc[8][2];
#pragma unroll
    for (int i = 0; i < 8; ++i) { acc[i][0] = 0.f; acc[i][1] = 0.f; }

    for (int kc = 0; kc < 64; kc += 32) {
#pragma unroll
        for (int i = 0; i < 2; ++i) {
            int vi = i * 256 + tid;
            int r = vi >> 3;
            int k4 = (vi & 7) << 2;
            int row = row0 + r;
            float4 v = make_float4(0.f, 0.f, 0.f, 0.f);
            if (row < N) v = *(const float4*)(A + (size_t)row * 64 + kc + k4);
            As[k4 + 0][r] = v.x; As[k4 + 1][r] = v.y; As[k4 + 2][r] = v.z; As[k4 + 3][r] = v.w;
        }
#pragma unroll
        for (int i = 0; i < 2; ++i) {
            int vi = i * 256 + tid;
            int k = vi >> 4;
            int c = (vi & 15) << 2;
            *(float4*)&Bs[k][c] = *(const float4*)(B1 + (size_t)(kc + k) * 64 + c);
        }
        __syncthreads();
#pragma unroll
        for (int k = 0; k < 32; ++k) {
            float4 a0 = *(const float4*)&As[k][rg * 8];
            float4 a1 = *(const float4*)&As[k][rg * 8 + 4];
            float a[8] = {a0.x, a0.y, a0.z, a0.w, a1.x, a1.y, a1.z, a1.w};
            float2 bv = *(const float2*)&Bs[k][cg * 2];
#pragma unroll
            for (int i = 0; i < 8; ++i) {
                acc[i][0] = fmaf(a[i], bv.x, acc[i][0]);
                acc[i][1] = fmaf(a[i], bv.y, acc[i][1]);
            }
        }
        __syncthreads();
    }

    float2 av = *(const float2*)(bias + cg * 2);
    float w0 = w2[cg * 2], w1 = w2[cg * 2 + 1];
    float bb = b2[0];
    float svals[8];
#pragma unroll
    for (int i = 0; i < 8; ++i) {
        float t0 = fmaxf(acc[i][0] + av.x, 0.f);
        float t1 = fmaxf(acc[i][1] + av.y, 0.f);
        float p = fmaf(t0, w0, t1 * w1);
#pragma unroll
        for (int d = 16; d >= 1; d >>= 1) p += __shfl_xor(p, d, 64);
        svals[i] = p;
    }
    float smx = -FLT_MAX;
    if (cg == 0) {
#pragma unroll
        for (int i = 0; i < 8; ++i) {
            int row = row0 + rg * 8 + i;
            if (row < N) {
                float s = svals[i] + bb;
                sbuf[row] = s;
                smx = fmaxf(smx, s);
            }
        }
    }
    smax[tid] = smx;
    __syncthreads();
    for (int d = 128; d >= 1; d >>= 1) {
        if (tid < d) smax[tid] = fmaxf(smax[tid], smax[tid + d]);
        __syncthreads();
    }
    if (tid == 0) atomicMax(red, enc_f(smax[0]));
}

// ---------------- aggregation: h = relu(segsum(m)/clip(deg,1) + [deg>0]*cl + r) ----------------
// wave per node, 64 lanes = 64 features, 8 gathers in flight
__global__ __launch_bounds__(256) void agg_kernel(
    const float* __restrict__ m, const float* __restrict__ r,
    const int* __restrict__ off, const int* __restrict__ srcs,
    const float* __restrict__ cl, float* __restrict__ hout, int N)
{
    int node = blockIdx.x * 4 + threadIdx.y;
    if (node >= N) return;
    int lane = threadIdx.x;
    int e0 = off[node], e1 = off[node + 1];
    float a[8];
#pragma unroll
    for (int i = 0; i < 8; ++i) a[i] = 0.f;

    for (int base = e0; base < e1; base += 64) {
        int e = base + lane;
        int sv = (e < e1) ? srcs[e] : 0;
        int cnt = min(e1 - base, 64);
        int j = 0;
        for (; j + 8 <= cnt; j += 8) {
            int s0 = __shfl(sv, j + 0), s1 = __shfl(sv, j + 1);
            int s2 = __shfl(sv, j + 2), s3 = __shfl(sv, j + 3);
            int s4 = __shfl(sv, j + 4), s5 = __shfl(sv, j + 5);
            int s6 = __shfl(sv, j + 6), s7 = __shfl(sv, j + 7);
            a[0] += m[(size_t)s0 * 64 + lane];
            a[1] += m[(size_t)s1 * 64 + lane];
            a[2] += m[(size_t)s2 * 64 + lane];
            a[3] += m[(size_t)s3 * 64 + lane];
            a[4] += m[(size_t)s4 * 64 + lane];
            a[5] += m[(size_t)s5 * 64 + lane];
            a[6] += m[(size_t)s6 * 64 + lane];
            a[7] += m[(size_t)s7 * 64 + lane];
        }
        for (; j < cnt; ++j) {
            int s = __shfl(sv, j);
            a[0] += m[(size_t)s * 64 + lane];
        }
    }
    float sum = ((a[0] + a[1]) + (a[2] + a[3])) + ((a[4] + a[5]) + (a[6] + a[7]));
    int deg = e1 - e0;
    float v = sum / (float)(deg > 0 ? deg : 1) + r[(size_t)node * 64 + lane];
    if (cl != nullptr && deg > 0) v += cl[lane];
    hout[(size_t)node * 64 + lane] = fmaxf(v, 0.f);
}

// ---------------- softmax reductions ----------------
__global__ __launch_bounds__(256) void sum_kernel(const float* __restrict__ s, const float* __restrict__ pos,
                                                  const unsigned* __restrict__ redmax, float* __restrict__ red, int N)
{
    float mx = dec_f(redmax[0]);
    float se = 0.f, px = 0.f, py = 0.f;
    for (int i = blockIdx.x * blockDim.x + threadIdx.x; i < N; i += gridDim.x * blockDim.x) {
        float e = expf(s[i] - mx);
        se += e;
        px = fmaf(e, pos[2 * i], px);
        py = fmaf(e, pos[2 * i + 1], py);
    }
#pragma unroll
    for (int d = 32; d >= 1; d >>= 1) {
        se += __shfl_xor(se, d, 64);
        px += __shfl_xor(px, d, 64);
        py += __shfl_xor(py, d, 64);
    }
    if ((threadIdx.x & 63) == 0) {
        atomicAdd(&red[1], se);
        atomicAdd(&red[2], px);
        atomicAdd(&red[3], py);
    }
}

__global__ __launch_bounds__(256) void final_kernel(const float* __restrict__ s, const unsigned* __restrict__ redmax,
                                                    const float* __restrict__ red, float* __restrict__ out, int N)
{
    float mx = dec_f(redmax[0]);
    float S = red[1];
    int i = blockIdx.x * blockDim.x + threadIdx.x;
    if (i < N) out[2 + i] = expf(s[i] - mx) / S;
    if (i == 0) {
        out[0] = red[2] / S;
        out[1] = red[3] / S;
    }
}

extern "C" void kernel_launch(void* const* d_in, const int* in_sizes, int n_in,
                              void* d_out, int out_size, void* d_ws, size_t ws_size,
                              hipStream_t stream)
{
    const float* x    = (const float*)d_in[0];
    const float* pos  = (const float*)d_in[1];
    const int*   ei   = (const int*)d_in[2];
    const int*   qids = (const int*)d_in[3];
    const float* qrs  = (const float*)d_in[4];
    const float* emb  = (const float*)d_in[5];
    const float* ew   = (const float*)d_in[6];
    const float* eb   = (const float*)d_in[7];
    const float* Wl0  = (const float*)d_in[8];
    const float* Wr0  = (const float*)d_in[9];
    const float* b0   = (const float*)d_in[10];
    const float* Wl1  = (const float*)d_in[11];
    const float* Wr1  = (const float*)d_in[12];
    const float* b1   = (const float*)d_in[13];
    const float* Wl2  = (const float*)d_in[14];
    const float* Wr2  = (const float*)d_in[15];
    const float* b2   = (const float*)d_in[16];
    const float* sw1  = (const float*)d_in[17];
    const float* sb1  = (const float*)d_in[18];
    const float* sw2  = (const float*)d_in[19];
    const float* sb2  = (const float*)d_in[20];

    const int N  = in_sizes[0] / 128;
    const int E  = in_sizes[2] / 2;
    const int NQ = in_sizes[3];
    const int NB = (N + 255) / 256;

    char* base = (char*)d_ws;
    size_t wsoff = 0;
    auto take = [&](size_t bytes) -> char* {
        char* p = base + wsoff;
        wsoff = (wsoff + bytes + 255) & ~(size_t)255;
        return p;
    };
    int*      deg    = (int*)take((size_t)N * 4);
    int*      offs   = (int*)take((size_t)(N + 1) * 4);
    int*      cursor = (int*)take((size_t)N * 4);
    int*      bsum   = (int*)take((size_t)NB * 4);
    int*      bbase  = (int*)take((size_t)NB * 4);
    int*      srcs   = (int*)take((size_t)E * 4);
    float*    zout   = (float*)take(192 * 4);   // zq[64], cl[64], crb[64]
    unsigned* red    = (unsigned*)take(16);     // [0]=max(enc) [1]=sumexp [2]=px [3]=py
    float*    mbuf   = (float*)take((size_t)N * 64 * 4);
    float*    rbuf   = (float*)take((size_t)N * 64 * 4);
    float*    hbuf   = (float*)take((size_t)N * 64 * 4);
    float*    sbuf   = (float*)take((size_t)N * 4);
    (void)ws_size; (void)n_in; (void)out_size;

    const int* esrc = ei;
    const int* edst = ei + E;

    hipMemsetAsync(deg, 0, (size_t)N * 4, stream);
    hipMemsetAsync(red, 0, 16, stream);

    encoder_kernel<<<1, 256, 0, stream>>>(qids, qrs, emb, ew, eb, Wl0, Wr0, b0, zout, NQ);
    count_kernel<<<(E + 255) / 256, 256, 0, stream>>>(edst, deg, E);
    scanA_kernel<<<NB, 256, 0, stream>>>(deg, offs, bsum, N);
    scanB_kernel<<<1, 256, 0, stream>>>(bsum, bbase, offs, NB, N);
    scanC_kernel<<<NB, 256, 0, stream>>>(offs, cursor, bbase, N);
    scatter_kernel<<<(E + 255) / 256, 256, 0, stream>>>(esrc, edst, cursor, srcs, E);

    int gblocks = (N + 63) / 64;
    dim3 ablk(64, 4);
    int ablocks = (N + 3) / 4;

    // layer 0: m = x@Wl0_top, r = x@Wr0_top + (zq@Wr0_bot + b0)
    gemm_kernel<128><<<gblocks, 256, 0, stream>>>(x, Wl0, Wr0, nullptr, zout + 128, mbuf, rbuf, N);
    agg_kernel<<<ablocks, ablk, 0, stream>>>(mbuf, rbuf, offs, srcs, zout + 64, hbuf, N);
    // layer 1
    gemm_kernel<64><<<gblocks, 256, 0, stream>>>(hbuf, Wl1, Wr1, nullptr, b1, mbuf, rbuf, N);
    agg_kernel<<<ablocks, ablk, 0, stream>>>(mbuf, rbuf, offs, srcs, nullptr, hbuf, N);
    // layer 2
    gemm_kernel<64><<<gblocks, 256, 0, stream>>>(hbuf, Wl2, Wr2, nullptr, b2, mbuf, rbuf, N);
    agg_kernel<<<ablocks, ablk, 0, stream>>>(mbuf, rbuf, offs, srcs, nullptr, hbuf, N);
    // fused scorer (writes sbuf + atomicMax into red[0])
    scorer_gemm_kernel<<<gblocks, 256, 0, stream>>>(hbuf, sw1, sb1, sw2, sb2, sbuf, red, N);

    sum_kernel<<<128, 256, 0, stream>>>(sbuf, pos, red, (float*)red, N);
    final_kernel<<<(N + 255) / 256, 256, 0, stream>>>(sbuf, red, (float*)red, (float*)d_out, N);
}

// Round 3
// 407.425 us; speedup vs baseline: 1.4650x; 1.0176x over previous
//
#include <hip/hip_runtime.h>
#include <cmath>
#include <cfloat>

#define DEV __device__ __forceinline__

DEV unsigned enc_f(float x) { unsigned u = __float_as_uint(x); return (u >> 31) ? ~u : (u | 0x80000000u); }
DEV float dec_f(unsigned u) { return __uint_as_float((u >> 31) ? (u & 0x7FFFFFFFu) : ~u); }

// ---------------- encoder: z_q, cl = zq@Wl0_bot, crb = zq@Wr0_bot + b0 ----------------
__global__ __launch_bounds__(256) void encoder_kernel(
    const int* __restrict__ ids, const float* __restrict__ rssi,
    const float* __restrict__ emb, const float* __restrict__ ew, const float* __restrict__ eb,
    const float* __restrict__ Wl0, const float* __restrict__ Wr0, const float* __restrict__ b0,
    float* __restrict__ zout, int NQ)
{
    __shared__ float zsh[4][64];
    __shared__ float zq[64];
    int j = threadIdx.x & 63;
    int g = threadIdx.x >> 6;
    float acc = 0.f;
    for (int q = g; q < NQ; q += 4) {
        int id = ids[q];
        const float* e = emb + (size_t)id * 32;
        float p = eb[j];
#pragma unroll
        for (int k = 0; k < 32; ++k) p = fmaf(e[k], ew[k * 64 + j], p);
        p = fmaf(rssi[q], ew[32 * 64 + j], p);
        acc += fmaxf(p, 0.f);
    }
    zsh[g][j] = acc;
    __syncthreads();
    if (g == 0) {
        float z = (zsh[0][j] + zsh[1][j] + zsh[2][j] + zsh[3][j]) / (float)NQ;
        zq[j] = z;
        zout[j] = z;
    }
    __syncthreads();
    if (g == 0) {
        float cl = 0.f, cr = 0.f;
        for (int k = 0; k < 64; ++k) {
            float zk = zq[k];
            cl = fmaf(zk, Wl0[(128 + k) * 64 + j], cl);
            cr = fmaf(zk, Wr0[(128 + k) * 64 + j], cr);
        }
        zout[64 + j] = cl;
        zout[128 + j] = cr + b0[j];
    }
}

// ---------------- CSR build ----------------
__global__ __launch_bounds__(256) void count_kernel(const int* __restrict__ dst, int* __restrict__ deg, int E)
{
    int i = blockIdx.x * 256 + threadIdx.x;
    if (i < E) atomicAdd(&deg[dst[i]], 1);
}

// phase A: per-block inclusive scan -> local exclusive in offs, block sum to bsum
__global__ __launch_bounds__(256) void scanA_kernel(const int* __restrict__ deg, int* __restrict__ offs,
                                                    int* __restrict__ bsum, int N)
{
    __shared__ int sh[256];
    int t = threadIdx.x;
    int i = blockIdx.x * 256 + t;
    int v = (i < N) ? deg[i] : 0;
    sh[t] = v;
    __syncthreads();
#pragma unroll
    for (int d = 1; d < 256; d <<= 1) {
        int u = (t >= d) ? sh[t - d] : 0;
        __syncthreads();
        sh[t] += u;
        __syncthreads();
    }
    if (i < N) offs[i] = sh[t] - v;
    if (t == 255) bsum[blockIdx.x] = sh[255];
}

// phase B: scan block sums, write bbase, offs[N]=total
__global__ __launch_bounds__(256) void scanB_kernel(const int* __restrict__ bsum, int* __restrict__ bbase,
                                                    int* __restrict__ offs, int NB, int N)
{
    __shared__ int sh[256];
    int t = threadIdx.x;
    int C = (NB + 255) >> 8;
    int c0 = t * C, c1 = min(c0 + C, NB);
    int s = 0;
    for (int i = c0; i < c1; ++i) s += bsum[i];
    sh[t] = s;
    __syncthreads();
#pragma unroll
    for (int d = 1; d < 256; d <<= 1) {
        int u = (t >= d) ? sh[t - d] : 0;
        __syncthreads();
        sh[t] += u;
        __syncthreads();
    }
    int run = (t > 0) ? sh[t - 1] : 0;
    for (int i = c0; i < c1; ++i) { bbase[i] = run; run += bsum[i]; }
    if (t == 255) offs[N] = sh[255];
}

// phase C: add block base, init cursor
__global__ __launch_bounds__(256) void scanC_kernel(int* __restrict__ offs, int* __restrict__ cursor,
                                                    const int* __restrict__ bbase, int N)
{
    int i = blockIdx.x * 256 + threadIdx.x;
    if (i < N) {
        int o = offs[i] + bbase[blockIdx.x];
        offs[i] = o;
        cursor[i] = o;
    }
}

// XCD-partitioned scatter: block (part = blockIdx&7) handles only dst in its node range.
// Each srcs region is then written by one XCD only -> full-line writebacks (kills the
// 16x partial-line write amplification seen in round 2). Edge list is re-read 8x but
// as coalesced streams. Correctness does NOT depend on the blockIdx->XCD mapping.
__global__ __launch_bounds__(256) void scatter_kernel(const int* __restrict__ src, const int* __restrict__ dst,
                                                      int* __restrict__ cursor, int* __restrict__ srcs,
                                                      int E, int N)
{
    const int part = blockIdx.x & 7;
    const int chunk = blockIdx.x >> 3;
    const int npart = (N + 7) >> 3;
    const int lo = part * npart;
    const int hi = min(lo + npart, N);
    const int base = chunk * 4096 + threadIdx.x;
#pragma unroll
    for (int it = 0; it < 16; ++it) {
        int i = base + it * 256;
        if (i < E) {
            int d = dst[i];
            if (d >= lo && d < hi) {
                int p = atomicAdd(&cursor[d], 1);
                srcs[p] = src[i];
            }
        }
    }
}

// ---------------- tiled fp32 GEMM (dual output): O1 = A@B1 (+add1), O2 = A@B2 (+add2) ----------------
template <int K>
__global__ __launch_bounds__(256) void gemm_kernel(
    const float* __restrict__ A, const float* __restrict__ B1, const float* __restrict__ B2,
    const float* __restrict__ add1, const float* __restrict__ add2,
    float* __restrict__ O1, float* __restrict__ O2, int N)
{
    __shared__ float As[32][68];   // [k][row], pad 68: 16B-aligned b128 reads, 2-way banks (free)
    __shared__ float Bs[32][128];

    const int tid = threadIdx.x;
    const int cg = tid & 31;
    const int rg = tid >> 5;
    const int row0 = blockIdx.x * 64;

    float acc[8][4];
#pragma unroll
    for (int i = 0; i < 8; ++i)
#pragma unroll
        for (int j = 0; j < 4; ++j) acc[i][j] = 0.f;

    for (int kc = 0; kc < K; kc += 32) {
#pragma unroll
        for (int i = 0; i < 2; ++i) {
            int vi = i * 256 + tid;
            int r = vi >> 3;
            int k4 = (vi & 7) << 2;
            int row = row0 + r;
            float4 v = make_float4(0.f, 0.f, 0.f, 0.f);
            if (row < N) v = *(const float4*)(A + (size_t)row * K + kc + k4);
            As[k4 + 0][r] = v.x; As[k4 + 1][r] = v.y; As[k4 + 2][r] = v.z; As[k4 + 3][r] = v.w;
        }
#pragma unroll
        for (int i = 0; i < 4; ++i) {
            int vi = i * 256 + tid;
            int k = vi >> 5;
            int c = (vi & 31) << 2;
            const float* sp = (c < 64) ? (B1 + (size_t)(kc + k) * 64 + c)
                                       : (B2 + (size_t)(kc + k) * 64 + (c - 64));
            *(float4*)&Bs[k][c] = *(const float4*)sp;
        }
        __syncthreads();
#pragma unroll
        for (int k = 0; k < 32; ++k) {
            float4 a0 = *(const float4*)&As[k][rg * 8];
            float4 a1 = *(const float4*)&As[k][rg * 8 + 4];
            float a[8] = {a0.x, a0.y, a0.z, a0.w, a1.x, a1.y, a1.z, a1.w};
            float4 bv = *(const float4*)&Bs[k][cg * 4];
            float b[4] = {bv.x, bv.y, bv.z, bv.w};
#pragma unroll
            for (int i = 0; i < 8; ++i)
#pragma unroll
                for (int j = 0; j < 4; ++j)
                    acc[i][j] = fmaf(a[i], b[j], acc[i][j]);
        }
        __syncthreads();
    }

    int c0 = cg * 4;
    float* O; int c; const float* addp;
    if (c0 < 64) { O = O1; c = c0; addp = add1; }
    else         { O = O2; c = c0 - 64; addp = add2; }
    float4 av = make_float4(0.f, 0.f, 0.f, 0.f);
    if (addp) av = *(const float4*)(addp + c);
#pragma unroll
    for (int i = 0; i < 8; ++i) {
        int row = row0 + rg * 8 + i;
        if (row < N) {
            float4 o;
            o.x = acc[i][0] + av.x; o.y = acc[i][1] + av.y;
            o.z = acc[i][2] + av.z; o.w = acc[i][3] + av.w;
            *(float4*)(O + (size_t)row * 64 + c) = o;
        }
    }
}

// ---------------- fused scorer: s = relu(h@w1+b1)@w2 + b2, block max -> atomicMax ----------------
__global__ __launch_bounds__(256) void scorer_gemm_kernel(
    const float* __restrict__ A, const float* __restrict__ B1,
    const float* __restrict__ bias, const float* __restrict__ w2, const float* __restrict__ b2,
    float* __restrict__ sbuf, unsigned* __restrict__ red, int N)
{
    __shared__ float As[32][68];
    __shared__ float Bs[32][64];
    __shared__ float smax[256];

    const int tid = threadIdx.x;
    const int cg = tid & 31;
    const int rg = tid >> 5;
    const int row0 = blockIdx.x * 64;

    float acc[8][2];
#pragma unroll
    for (int i = 0; i < 8; ++i) { acc[i][0] = 0.f; acc[i][1] = 0.f; }

    for (int kc = 0; kc < 64; kc += 32) {
#pragma unroll
        for (int i = 0; i < 2; ++i) {
            int vi = i * 256 + tid;
            int r = vi >> 3;
            int k4 = (vi & 7) << 2;
            int row = row0 + r;
            float4 v = make_float4(0.f, 0.f, 0.f, 0.f);
            if (row < N) v = *(const float4*)(A + (size_t)row * 64 + kc + k4);
            As[k4 + 0][r] = v.x; As[k4 + 1][r] = v.y; As[k4 + 2][r] = v.z; As[k4 + 3][r] = v.w;
        }
#pragma unroll
        for (int i = 0; i < 2; ++i) {
            int vi = i * 256 + tid;
            int k = vi >> 4;
            int c = (vi & 15) << 2;
            *(float4*)&Bs[k][c] = *(const float4*)(B1 + (size_t)(kc + k) * 64 + c);
        }
        __syncthreads();
#pragma unroll
        for (int k = 0; k < 32; ++k) {
            float4 a0 = *(const float4*)&As[k][rg * 8];
            float4 a1 = *(const float4*)&As[k][rg * 8 + 4];
            float a[8] = {a0.x, a0.y, a0.z, a0.w, a1.x, a1.y, a1.z, a1.w};
            float2 bv = *(const float2*)&Bs[k][cg * 2];
#pragma unroll
            for (int i = 0; i < 8; ++i) {
                acc[i][0] = fmaf(a[i], bv.x, acc[i][0]);
                acc[i][1] = fmaf(a[i], bv.y, acc[i][1]);
            }
        }
        __syncthreads();
    }

    float2 av = *(const float2*)(bias + cg * 2);
    float w0 = w2[cg * 2], w1 = w2[cg * 2 + 1];
    float bb = b2[0];
    float svals[8];
#pragma unroll
    for (int i = 0; i < 8; ++i) {
        float t0 = fmaxf(acc[i][0] + av.x, 0.f);
        float t1 = fmaxf(acc[i][1] + av.y, 0.f);
        float p = fmaf(t0, w0, t1 * w1);
#pragma unroll
        for (int d = 16; d >= 1; d >>= 1) p += __shfl_xor(p, d, 64);
        svals[i] = p;
    }
    float smx = -FLT_MAX;
    if (cg == 0) {
#pragma unroll
        for (int i = 0; i < 8; ++i) {
            int row = row0 + rg * 8 + i;
            if (row < N) {
                float s = svals[i] + bb;
                sbuf[row] = s;
                smx = fmaxf(smx, s);
            }
        }
    }
    smax[tid] = smx;
    __syncthreads();
    for (int d = 128; d >= 1; d >>= 1) {
        if (tid < d) smax[tid] = fmaxf(smax[tid], smax[tid + d]);
        __syncthreads();
    }
    if (tid == 0) atomicMax(red, enc_f(smax[0]));
}

// ---------------- aggregation: h = relu(segsum(m)/clip(deg,1) + [deg>0]*cl + r) ----------------
// wave per node, 64 lanes = 64 features, up to 16 gathers in flight
__global__ __launch_bounds__(256) void agg_kernel(
    const float* __restrict__ m, const float* __restrict__ r,
    const int* __restrict__ off, const int* __restrict__ srcs,
    const float* __restrict__ cl, float* __restrict__ hout, int N)
{
    int node = blockIdx.x * 4 + threadIdx.y;
    if (node >= N) return;
    int lane = threadIdx.x;
    int e0 = off[node], e1 = off[node + 1];
    float a[16];
#pragma unroll
    for (int i = 0; i < 16; ++i) a[i] = 0.f;

    for (int base = e0; base < e1; base += 64) {
        int e = base + lane;
        int sv = (e < e1) ? srcs[e] : 0;
        int cnt = min(e1 - base, 64);
        int j = 0;
        for (; j + 16 <= cnt; j += 16) {
#pragma unroll
            for (int u = 0; u < 16; ++u) {
                int s = __shfl(sv, j + u);
                a[u] += m[(size_t)s * 64 + lane];
            }
        }
        for (; j + 4 <= cnt; j += 4) {
#pragma unroll
            for (int u = 0; u < 4; ++u) {
                int s = __shfl(sv, j + u);
                a[u] += m[(size_t)s * 64 + lane];
            }
        }
        for (; j < cnt; ++j) {
            int s = __shfl(sv, j);
            a[0] += m[(size_t)s * 64 + lane];
        }
    }
    float sum = 0.f;
#pragma unroll
    for (int i = 0; i < 16; ++i) sum += a[i];
    int deg = e1 - e0;
    float v = sum / (float)(deg > 0 ? deg : 1) + r[(size_t)node * 64 + lane];
    if (cl != nullptr && deg > 0) v += cl[lane];
    hout[(size_t)node * 64 + lane] = fmaxf(v, 0.f);
}

// ---------------- softmax reductions ----------------
__global__ __launch_bounds__(256) void sum_kernel(const float* __restrict__ s, const float* __restrict__ pos,
                                                  const unsigned* __restrict__ redmax, float* __restrict__ red, int N)
{
    float mx = dec_f(redmax[0]);
    float se = 0.f, px = 0.f, py = 0.f;
    for (int i = blockIdx.x * blockDim.x + threadIdx.x; i < N; i += gridDim.x * blockDim.x) {
        float e = expf(s[i] - mx);
        se += e;
        px = fmaf(e, pos[2 * i], px);
        py = fmaf(e, pos[2 * i + 1], py);
    }
#pragma unroll
    for (int d = 32; d >= 1; d >>= 1) {
        se += __shfl_xor(se, d, 64);
        px += __shfl_xor(px, d, 64);
        py += __shfl_xor(py, d, 64);
    }
    if ((threadIdx.x & 63) == 0) {
        atomicAdd(&red[1], se);
        atomicAdd(&red[2], px);
        atomicAdd(&red[3], py);
    }
}

__global__ __launch_bounds__(256) void final_kernel(const float* __restrict__ s, const unsigned* __restrict__ redmax,
                                                    const float* __restrict__ red, float* __restrict__ out, int N)
{
    float mx = dec_f(redmax[0]);
    float S = red[1];
    int i = blockIdx.x * blockDim.x + threadIdx.x;
    if (i < N) out[2 + i] = expf(s[i] - mx) / S;
    if (i == 0) {
        out[0] = red[2] / S;
        out[1] = red[3] / S;
    }
}

extern "C" void kernel_launch(void* const* d_in, const int* in_sizes, int n_in,
                              void* d_out, int out_size, void* d_ws, size_t ws_size,
                              hipStream_t stream)
{
    const float* x    = (const float*)d_in[0];
    const float* pos  = (const float*)d_in[1];
    const int*   ei   = (const int*)d_in[2];
    const int*   qids = (const int*)d_in[3];
    const float* qrs  = (const float*)d_in[4];
    const float* emb  = (const float*)d_in[5];
    const float* ew   = (const float*)d_in[6];
    const float* eb   = (const float*)d_in[7];
    const float* Wl0  = (const float*)d_in[8];
    const float* Wr0  = (const float*)d_in[9];
    const float* b0   = (const float*)d_in[10];
    const float* Wl1  = (const float*)d_in[11];
    const float* Wr1  = (const float*)d_in[12];
    const float* b1   = (const float*)d_in[13];
    const float* Wl2  = (const float*)d_in[14];
    const float* Wr2  = (const float*)d_in[15];
    const float* b2   = (const float*)d_in[16];
    const float* sw1  = (const float*)d_in[17];
    const float* sb1  = (const float*)d_in[18];
    const float* sw2  = (const float*)d_in[19];
    const float* sb2  = (const float*)d_in[20];

    const int N  = in_sizes[0] / 128;
    const int E  = in_sizes[2] / 2;
    const int NQ = in_sizes[3];
    const int NB = (N + 255) / 256;

    char* base = (char*)d_ws;
    size_t wsoff = 0;
    auto take = [&](size_t bytes) -> char* {
        char* p = base + wsoff;
        wsoff = (wsoff + bytes + 255) & ~(size_t)255;
        return p;
    };
    int*      deg    = (int*)take((size_t)N * 4);
    int*      offs   = (int*)take((size_t)(N + 1) * 4);
    int*      cursor = (int*)take((size_t)N * 4);
    int*      bsum   = (int*)take((size_t)NB * 4);
    int*      bbase  = (int*)take((size_t)NB * 4);
    int*      srcs   = (int*)take((size_t)E * 4);
    float*    zout   = (float*)take(192 * 4);   // zq[64], cl[64], crb[64]
    unsigned* red    = (unsigned*)take(16);     // [0]=max(enc) [1]=sumexp [2]=px [3]=py
    float*    mbuf   = (float*)take((size_t)N * 64 * 4);
    float*    rbuf   = (float*)take((size_t)N * 64 * 4);
    float*    hbuf   = (float*)take((size_t)N * 64 * 4);
    float*    sbuf   = (float*)take((size_t)N * 4);
    (void)ws_size; (void)n_in; (void)out_size;

    const int* esrc = ei;
    const int* edst = ei + E;

    hipMemsetAsync(deg, 0, (size_t)N * 4, stream);
    hipMemsetAsync(red, 0, 16, stream);

    encoder_kernel<<<1, 256, 0, stream>>>(qids, qrs, emb, ew, eb, Wl0, Wr0, b0, zout, NQ);
    count_kernel<<<(E + 255) / 256, 256, 0, stream>>>(edst, deg, E);
    scanA_kernel<<<NB, 256, 0, stream>>>(deg, offs, bsum, N);
    scanB_kernel<<<1, 256, 0, stream>>>(bsum, bbase, offs, NB, N);
    scanC_kernel<<<NB, 256, 0, stream>>>(offs, cursor, bbase, N);
    int schunks = (E + 4095) / 4096;
    scatter_kernel<<<schunks * 8, 256, 0, stream>>>(esrc, edst, cursor, srcs, E, N);

    int gblocks = (N + 63) / 64;
    dim3 ablk(64, 4);
    int ablocks = (N + 3) / 4;

    // layer 0: m = x@Wl0_top, r = x@Wr0_top + (zq@Wr0_bot + b0)
    gemm_kernel<128><<<gblocks, 256, 0, stream>>>(x, Wl0, Wr0, nullptr, zout + 128, mbuf, rbuf, N);
    agg_kernel<<<ablocks, ablk, 0, stream>>>(mbuf, rbuf, offs, srcs, zout + 64, hbuf, N);
    // layer 1
    gemm_kernel<64><<<gblocks, 256, 0, stream>>>(hbuf, Wl1, Wr1, nullptr, b1, mbuf, rbuf, N);
    agg_kernel<<<ablocks, ablk, 0, stream>>>(mbuf, rbuf, offs, srcs, nullptr, hbuf, N);
    // layer 2
    gemm_kernel<64><<<gblocks, 256, 0, stream>>>(hbuf, Wl2, Wr2, nullptr, b2, mbuf, rbuf, N);
    agg_kernel<<<ablocks, ablk, 0, stream>>>(mbuf, rbuf, offs, srcs, nullptr, hbuf, N);
    // fused scorer (writes sbuf + atomicMax into red[0])
    scorer_gemm_kernel<<<gblocks, 256, 0, stream>>>(hbuf, sw1, sb1, sw2, sb2, sbuf, red, N);

    sum_kernel<<<128, 256, 0, stream>>>(sbuf, pos, red, (float*)red, N);
    final_kernel<<<(N + 255) / 256, 256, 0, stream>>>(sbuf, red, (float*)red, (float*)d_out, N);
}